// Round 1
// baseline (1704.806 us; speedup 1.0000x reference)
//
#include <hip/hip_runtime.h>
#include <math.h>

#define BETA_C   0.99f
#define TOL_C    1e-4f
#define MAXIT_C  1000
#define EPS_C    1e-3f
#define BN       65536
#define NN       32
#define HFD      25
#define HVD      128
#define KVD      8

// softplus = jax.nn.softplus = logaddexp(x,0) = max(x,0)+log1p(exp(-|x|))
__device__ __forceinline__ float sp_(float x) {
    return fmaxf(x, 0.f) + log1pf(expf(-fabsf(x)));
}
// d softplus / dx = sigmoid
__device__ __forceinline__ float sig_(float x) {
    return 1.f / (1.f + expf(-x));
}

// V(fx * g) with n2 = sum(fx^2).  TAN => also dV/dg (forward-mode dual).
// 128-wide hidden processed in 2 chunks of 64 to keep acc/dacc <= 128 VGPRs.
template <bool TAN>
__device__ __forceinline__ void veval(
    const float* __restrict__ fx, float g, float n2,
    const float* __restrict__ vW1, const float* __restrict__ vb1,
    const float* __restrict__ vW2, const float* __restrict__ vb2,
    const float* __restrict__ vW3, const float* __restrict__ vb3,
    const float* __restrict__ h0g, float& Vout, float& dVout)
{
    float out[KVD], dout[KVD];
#pragma unroll
    for (int c = 0; c < KVD; ++c) { out[c] = vb3[c]; dout[c] = 0.f; }

#pragma unroll 1
    for (int ch = 0; ch < 2; ++ch) {
        float acc[64], dacc[64];
#pragma unroll
        for (int j = 0; j < 64; ++j) { acc[j] = 0.f; dacc[j] = 0.f; }

#pragma unroll 1
        for (int k = 0; k < HVD; ++k) {
            // u_k = fx . vW1[:,k]   (first layer, gamma-invariant direction)
            float u0 = 0.f, u1 = 0.f, u2 = 0.f, u3 = 0.f;
#pragma unroll
            for (int i = 0; i < NN; i += 4) {
                u0 = fmaf(fx[i + 0], vW1[(i + 0) * HVD + k], u0);
                u1 = fmaf(fx[i + 1], vW1[(i + 1) * HVD + k], u1);
                u2 = fmaf(fx[i + 2], vW1[(i + 2) * HVD + k], u2);
                u3 = fmaf(fx[i + 3], vW1[(i + 3) * HVD + k], u3);
            }
            float u = (u0 + u1) + (u2 + u3);
            float pre = fmaf(g, u, vb1[k]);
            float h1 = sp_(pre);
            float dh1 = TAN ? sig_(pre) * u : 0.f;
            const float* w2r = vW2 + k * HVD + ch * 64;
#pragma unroll
            for (int j = 0; j < 64; ++j) {
                float w = w2r[j];
                acc[j] = fmaf(h1, w, acc[j]);
                if (TAN) dacc[j] = fmaf(dh1, w, dacc[j]);
            }
        }
#pragma unroll
        for (int j = 0; j < 64; ++j) {
            int jj = ch * 64 + j;
            float pre2 = acc[j] + vb2[jj];
            float h2 = sp_(pre2);
            float dh2 = TAN ? sig_(pre2) * dacc[j] : 0.f;
            const float* w3r = vW3 + jj * KVD;
#pragma unroll
            for (int c = 0; c < KVD; ++c) {
                float w = w3r[c];
                out[c] = fmaf(h2, w, out[c]);
                if (TAN) dout[c] = fmaf(dh2, w, dout[c]);
            }
        }
    }
    float vv = 0.f, dv = 0.f;
#pragma unroll
    for (int c = 0; c < KVD; ++c) {
        float d = out[c] - h0g[c];
        vv = fmaf(d, d, vv);
        if (TAN) dv = fmaf(d, dout[c], dv);
    }
    vv += EPS_C * (g * g) * n2;
    Vout = vv;
    if (TAN) dVout = 2.f * dv + 2.f * EPS_C * g * n2;
}

// ---- h0 = V-MLP(0) : weight-only, one tiny block --------------------------
__global__ __launch_bounds__(128) void k_h0(
    const float* __restrict__ vb1, const float* __restrict__ vW2,
    const float* __restrict__ vb2, const float* __restrict__ vW3,
    const float* __restrict__ vb3, float* __restrict__ h0g)
{
    __shared__ float h1s[HVD];
    __shared__ float h2s[HVD];
    int j = threadIdx.x;
    h1s[j] = sp_(vb1[j]);
    __syncthreads();
    float a = vb2[j];
    for (int k = 0; k < HVD; ++k) a = fmaf(h1s[k], vW2[k * HVD + j], a);
    h2s[j] = sp_(a);
    __syncthreads();
    if (j < KVD) {
        float acc = vb3[j];
        for (int k = 0; k < HVD; ++k) acc = fmaf(h2s[k], vW3[k * KVD + j], acc);
        h0g[j] = acc;
    }
}

// ---- setup: fhat, V(x)->target, V(fhatx), active-compaction ---------------
__global__ __launch_bounds__(256) void k_setup(
    const float* __restrict__ x_g,
    const float* __restrict__ fW1, const float* __restrict__ fb1,
    const float* __restrict__ fW2, const float* __restrict__ fb2,
    const float* __restrict__ fW3, const float* __restrict__ fb3,
    const float* __restrict__ vW1, const float* __restrict__ vb1,
    const float* __restrict__ vW2, const float* __restrict__ vb2,
    const float* __restrict__ vW3, const float* __restrict__ vb3,
    const float* __restrict__ h0g,
    float* __restrict__ out,
    int* __restrict__ cnt, int* __restrict__ list, float* __restrict__ tgt)
{
    int s = blockIdx.x * 256 + threadIdx.x;

    float xr[NN];
    const float4* xp = (const float4*)(x_g + (size_t)s * NN);
#pragma unroll
    for (int i = 0; i < NN / 4; ++i) {
        float4 v = xp[i];
        xr[4 * i + 0] = v.x; xr[4 * i + 1] = v.y;
        xr[4 * i + 2] = v.z; xr[4 * i + 3] = v.w;
    }

    // fhat: 32 -> softplus 25 -> softplus 25 -> 32
    float h1f[HFD];
#pragma unroll
    for (int j = 0; j < HFD; ++j) {
        float a = fb1[j];
#pragma unroll
        for (int i = 0; i < NN; ++i) a = fmaf(xr[i], fW1[i * HFD + j], a);
        h1f[j] = sp_(a);
    }
    float h2f[HFD];
#pragma unroll
    for (int j = 0; j < HFD; ++j) {
        float a = fb2[j];
#pragma unroll
        for (int i = 0; i < HFD; ++i) a = fmaf(h1f[i], fW2[i * HFD + j], a);
        h2f[j] = sp_(a);
    }
    float fx[NN];
#pragma unroll
    for (int j = 0; j < NN; ++j) {
        float a = fb3[j];
#pragma unroll
        for (int i = 0; i < HFD; ++i) a = fmaf(h2f[i], fW3[i * NN + j], a);
        fx[j] = a;
    }

    // write fhatx (final answer for non-violating samples; solver rescales rest)
    float4* op = (float4*)(out + (size_t)s * NN);
#pragma unroll
    for (int i = 0; i < NN / 4; ++i)
        op[i] = make_float4(fx[4 * i], fx[4 * i + 1], fx[4 * i + 2], fx[4 * i + 3]);

    float n2x = 0.f, n2f = 0.f;
#pragma unroll
    for (int i = 0; i < NN; ++i) { n2x = fmaf(xr[i], xr[i], n2x); n2f = fmaf(fx[i], fx[i], n2f); }

    float Vx, dd;
    veval<false>(xr, 1.f, n2x, vW1, vb1, vW2, vb2, vW3, vb3, h0g, Vx, dd);
    float target = BETA_C * Vx;

    float v1;
    veval<false>(fx, 1.f, n2f, vW1, vb1, vW2, vb2, vW3, vb3, h0g, v1, dd);

    bool active = (v1 - target) > 0.f;

    // block-level compaction: one atomicAdd per block
    __shared__ int wbase[4];
    __shared__ int bbase;
    unsigned long long bal = __ballot(active);
    int lane = threadIdx.x & 63, wv = threadIdx.x >> 6;
    int rank = __popcll(bal & ((1ull << lane) - 1ull));
    if (lane == 0) wbase[wv] = __popcll(bal);
    __syncthreads();
    if (threadIdx.x == 0) {
        int tot = 0;
        for (int i = 0; i < 4; ++i) { int c = wbase[i]; wbase[i] = tot; tot += c; }
        bbase = atomicAdd(cnt, tot);
    }
    __syncthreads();
    if (active) {
        int p = bbase + wbase[wv] + rank;
        list[p] = s;
        tgt[p] = target;
    }
}

// ---- solver: per-thread Newton + bisection, dual-number V ------------------
__global__ __launch_bounds__(64) void k_solve(
    const float* __restrict__ vW1, const float* __restrict__ vb1,
    const float* __restrict__ vW2, const float* __restrict__ vb2,
    const float* __restrict__ vW3, const float* __restrict__ vb3,
    const float* __restrict__ h0g,
    float* __restrict__ out,
    const int* __restrict__ cnt, const int* __restrict__ list,
    const float* __restrict__ tgt)
{
    int t = blockIdx.x * 64 + threadIdx.x;
    if (t >= *cnt) return;
    int s = list[t];

    float fx[NN];
    float4* op = (float4*)(out + (size_t)s * NN);
#pragma unroll
    for (int i = 0; i < NN / 4; ++i) {
        float4 v = op[i];
        fx[4 * i + 0] = v.x; fx[4 * i + 1] = v.y;
        fx[4 * i + 2] = v.z; fx[4 * i + 3] = v.w;
    }
    float n2 = 0.f;
#pragma unroll
    for (int i = 0; i < NN; ++i) n2 = fmaf(fx[i], fx[i], n2);

    float target = tgt[t];
    float h0l[KVD];
#pragma unroll
    for (int c = 0; c < KVD; ++c) h0l[c] = h0g[c];

    float gamma = 1.f, e1 = 0.f, e2 = 1.f;
    float v_e1 = 0.f;   // V(fx*0) == 0 bitwise (mlp(0)==h0)
    float v_e2 = 0.f;   // set from first dual eval (V at gamma=1)

    int it = 0;
    while (it < MAXIT_C) {
        float vp, dv;
        veval<true>(fx, gamma, n2, vW1, vb1, vW2, vb2, vW3, vb3, h0l, vp, dv);
        if (it == 0) {
            v_e2 = vp;                 // V(fx*1)
        } else if (fabsf(vp - target) <= TOL_C) {
            break;                     // reference's post-body mask check
        }
        float newt = gamma - (vp - target) / dv;
        // in-range & finite (NaN fails both comparisons -> bisect)
        bool good = (newt >= e1) && (newt <= e2);
        if (good) {
            gamma = newt;
            ++it;
        } else {
            float a = 0.5f * (e1 + e2);
            float va, du;
            veval<false>(fx, a, n2, vW1, vb1, vW2, vb2, vW3, vb3, h0l, va, du);
            float da = va - target, d1 = v_e1 - target, d2 = v_e2 - target;
            float sa = (da > 0.f) ? 1.f : ((da < 0.f) ? -1.f : 0.f);
            float s1 = (d1 > 0.f) ? 1.f : ((d1 < 0.f) ? -1.f : 0.f);
            float s2 = (d2 > 0.f) ? 1.f : ((d2 < 0.f) ? -1.f : 0.f);
            if (sa * s1 < 0.f) { e2 = a; v_e2 = va; }
            if (sa * s2 < 0.f) { e1 = a; v_e1 = va; }
            gamma = a;
            ++it;
            if (fabsf(va - target) <= TOL_C) break;
        }
    }

#pragma unroll
    for (int i = 0; i < NN / 4; ++i)
        op[i] = make_float4(fx[4 * i + 0] * gamma, fx[4 * i + 1] * gamma,
                            fx[4 * i + 2] * gamma, fx[4 * i + 3] * gamma);
}

extern "C" void kernel_launch(void* const* d_in, const int* in_sizes, int n_in,
                              void* d_out, int out_size, void* d_ws, size_t ws_size,
                              hipStream_t stream)
{
    const float* x   = (const float*)d_in[0];
    const float* fW1 = (const float*)d_in[1];
    const float* fb1 = (const float*)d_in[2];
    const float* fW2 = (const float*)d_in[3];
    const float* fb2 = (const float*)d_in[4];
    const float* fW3 = (const float*)d_in[5];
    const float* fb3 = (const float*)d_in[6];
    const float* vW1 = (const float*)d_in[7];
    const float* vb1 = (const float*)d_in[8];
    const float* vW2 = (const float*)d_in[9];
    const float* vb2 = (const float*)d_in[10];
    const float* vW3 = (const float*)d_in[11];
    const float* vb3 = (const float*)d_in[12];
    float* out = (float*)d_out;

    char* ws = (char*)d_ws;
    int*   cnt  = (int*)ws;                                  // 4 B
    float* h0g  = (float*)(ws + 64);                         // 8 floats
    int*   list = (int*)(ws + 128);                          // BN ints
    float* tgt  = (float*)(ws + 128 + (size_t)BN * 4);       // BN floats

    hipMemsetAsync(cnt, 0, sizeof(int), stream);

    hipLaunchKernelGGL(k_h0, dim3(1), dim3(HVD), 0, stream,
                       vb1, vW2, vb2, vW3, vb3, h0g);

    hipLaunchKernelGGL(k_setup, dim3(BN / 256), dim3(256), 0, stream,
                       x, fW1, fb1, fW2, fb2, fW3, fb3,
                       vW1, vb1, vW2, vb2, vW3, vb3,
                       h0g, out, cnt, list, tgt);

    hipLaunchKernelGGL(k_solve, dim3(BN / 64), dim3(64), 0, stream,
                       vW1, vb1, vW2, vb2, vW3, vb3,
                       h0g, out, cnt, list, tgt);
}